// Round 6
// baseline (146.739 us; speedup 1.0000x reference)
//
#include <hip/hip_runtime.h>
#include <hip/hip_fp16.h>
#include <stdint.h>

#define NROWS 4096
#define DIM   512
#define SLAB  64            // rows per block (A-slab in LDS)
#define CHUNK 256           // cols per block; wave covers 64 cols
#define GRID  ((NROWS / SLAB) * (NROWS / CHUNK))   // 64 * 16 = 1024 blocks = 4/CU
#define ROWB  1088          // LDS row stride bytes (1024 + 64; stride = 16 banks mod 32)

typedef float    f32x4 __attribute__((ext_vector_type(4)));
typedef _Float16 f16x8 __attribute__((ext_vector_type(8)));

// workspace layout (bytes)
#define OFF_XH   0u
#define OFF_SQ   (NROWS * DIM * 2u)          // 4,194,304
#define OFF_LAB  (OFF_SQ + NROWS * 4u)
#define OFF_ACC  (OFF_LAB + NROWS * 4u)      // [f s1][f s2][u cnt][u done]

// ---------------- prep: fp32 -> fp16, sq rows (fp32 exact), labels -> i32, zero accum
__global__ __launch_bounds__(256) void prep_kernel(
    const float* __restrict__ X, const long long* __restrict__ lab,
    unsigned short* __restrict__ Xh, float* __restrict__ sq,
    int* __restrict__ labi, unsigned* __restrict__ accum)
{
  int t = threadIdx.x;
  int gid = blockIdx.x * 256 + t;
  if (gid < 4) accum[gid] = 0u;
  if (gid < NROWS) labi[gid] = (int)lab[gid];

  int wave = t >> 6, lane = t & 63;
  int row = blockIdx.x * 4 + wave;              // 1024 blocks * 4 rows
  const float4* Xr = (const float4*)(X + (size_t)row * DIM);
  float4 a = Xr[lane * 2];
  float4 b = Xr[lane * 2 + 1];

  uint4 pk;
  pk.x = (unsigned)__half_as_ushort(__float2half(a.x)) | ((unsigned)__half_as_ushort(__float2half(a.y)) << 16);
  pk.y = (unsigned)__half_as_ushort(__float2half(a.z)) | ((unsigned)__half_as_ushort(__float2half(a.w)) << 16);
  pk.z = (unsigned)__half_as_ushort(__float2half(b.x)) | ((unsigned)__half_as_ushort(__float2half(b.y)) << 16);
  pk.w = (unsigned)__half_as_ushort(__float2half(b.z)) | ((unsigned)__half_as_ushort(__float2half(b.w)) << 16);
  *(uint4*)(Xh + (size_t)row * DIM + lane * 8) = pk;

  float s = a.x*a.x + a.y*a.y + a.z*a.z + a.w*a.w
          + b.x*b.x + b.y*b.y + b.z*b.z + b.w*b.w;
  #pragma unroll
  for (int off = 32; off; off >>= 1) s += __shfl_down(s, off, 64);
  if (lane == 0) sq[row] = s;
}

// ---------------- main: A-slab in LDS once; each wave streams a 64x64 output tile
// per pass with 4x4 register blocking (16 MFMA per k-step); B-frags straight from
// global (L2-hot, full 64B-line use). No barriers after staging.
__global__ __launch_bounds__(256) void pair_kernel(
    const unsigned short* __restrict__ Xh, const float* __restrict__ sq,
    const int* __restrict__ labi, const float* __restrict__ marginp,
    float* __restrict__ accum, float* __restrict__ out)
{
  __shared__ char  Asl[SLAB * ROWB];     // 69,632 B -> 2 blocks/CU resident
  __shared__ float sRow[SLAB];
  __shared__ int   lRow[SLAB];
  __shared__ float rs1[4], rs2[4];
  __shared__ int   rc[4];

  int t = threadIdx.x;
  int bi = blockIdx.x >> 4;              // 64 row-slabs
  int jc = blockIdx.x & 15;              // 16 column chunks
  int rowbase = bi * SLAB;
  int colbase = jc * CHUNK;

  // ---- stage A slab once: coalesced 16B loads -> padded LDS rows
  {
    int r4 = t >> 6;                     // 0..3
    int ch = t & 63;                     // 16B unit within a 1KB row
    #pragma unroll
    for (int p = 0; p < 16; ++p) {
      int row = p * 4 + r4;
      uint4 v = *(const uint4*)(Xh + (size_t)(rowbase + row) * DIM + ch * 8);
      *(uint4*)(Asl + row * ROWB + ch * 16) = v;
    }
  }
  if (t < SLAB) { sRow[t] = sq[rowbase + t]; lRow[t] = labi[rowbase + t]; }
  __syncthreads();                       // the ONLY staging barrier

  int wave = t >> 6, lane = t & 63;
  int quad = lane >> 4, ml = lane & 15;
  int wcol = colbase + wave * 64;        // this wave's 64-col stripe

  // B fragment base pointers: lane (quad,ml) of col-tile ct reads row (wcol+ct*16+ml),
  // bytes quad*16 + k*64 -> the 4 quads fully consume each 64B line.
  const char* bptr[4];
  #pragma unroll
  for (int ct = 0; ct < 4; ++ct)
    bptr[ct] = (const char*)(Xh + (size_t)(wcol + ct * 16 + ml) * DIM + quad * 8);

  f32x4 acc[4][4] = {};                  // [rt][ct], 64 VGPRs

  #pragma unroll
  for (int k = 0; k < 16; ++k) {
    f16x8 bfr[4], afr[4];
    #pragma unroll
    for (int ct = 0; ct < 4; ++ct)
      bfr[ct] = *(const f16x8*)(bptr[ct] + k * 64);
    const char* abase = Asl + k * 64 + quad * 16;
    #pragma unroll
    for (int rt = 0; rt < 4; ++rt)
      afr[rt] = *(const f16x8*)(abase + (rt * 16 + ml) * ROWB);
    #pragma unroll
    for (int rt = 0; rt < 4; ++rt)
      #pragma unroll
      for (int ct = 0; ct < 4; ++ct)
        acc[rt][ct] = __builtin_amdgcn_mfma_f32_16x16x32_f16(afr[rt], bfr[ct], acc[rt][ct], 0, 0, 0);
  }

  // ---- fused loss epilogue; C/D: col=lane&15, row=(lane>>4)*4+reg
  float margin = *marginp;
  float s1 = 0.f, s2 = 0.f;
  int cnt = 0;
  #pragma unroll
  for (int ct = 0; ct < 4; ++ct) {
    int col = wcol + ct * 16 + ml;
    float sqc = sq[col];
    int   lc  = labi[col];
    #pragma unroll
    for (int rt = 0; rt < 4; ++rt) {
      int rbase = rt * 16 + quad * 4;
      #pragma unroll
      for (int i = 0; i < 4; ++i) {
        int row = rbase + i;
        float d = sRow[row] + sqc - 2.0f * acc[rt][ct][i];
        d = fmaxf(d, 0.0f);
        if (lRow[row] == lc) { s1 += d; cnt++; }
        else                 { s2 += fmaxf(margin - d, 0.0f); }
      }
    }
  }

  // ---- block reduction + device accumulation
  #pragma unroll
  for (int off = 32; off; off >>= 1) {
    s1  += __shfl_down(s1, off, 64);
    s2  += __shfl_down(s2, off, 64);
    cnt += __shfl_down(cnt, off, 64);
  }
  if (lane == 0) { rs1[wave] = s1; rs2[wave] = s2; rc[wave] = cnt; }
  __syncthreads();
  if (t == 0) {
    float S1 = 0.f, S2 = 0.f;
    int C = 0;
    for (int w = 0; w < 4; ++w) { S1 += rs1[w]; S2 += rs2[w]; C += rc[w]; }
    atomicAdd(&accum[0], S1);
    atomicAdd(&accum[1], S2);
    atomicAdd((unsigned*)accum + 2, (unsigned)C);
    __threadfence();
    unsigned prev = atomicAdd((unsigned*)accum + 3, 1u);
    if (prev == GRID - 1) {
      float s1v = atomicAdd(&accum[0], 0.0f);
      float s2v = atomicAdd(&accum[1], 0.0f);
      unsigned c1 = atomicAdd((unsigned*)accum + 2, 0u);
      double zn1 = (double)c1;
      double zn2 = (double)NROWS * (double)NROWS - zn1;
      out[0] = (float)(0.5 * ((double)s1v / zn1 + (double)s2v / zn2));
    }
  }
}

extern "C" void kernel_launch(void* const* d_in, const int* in_sizes, int n_in,
                              void* d_out, int out_size, void* d_ws, size_t ws_size,
                              hipStream_t stream) {
  const float*     X      = (const float*)d_in[0];
  const long long* lab    = (const long long*)d_in[1];
  const float*     margin = (const float*)d_in[2];
  float*           out    = (float*)d_out;

  char* ws = (char*)d_ws;
  unsigned short* Xh   = (unsigned short*)(ws + OFF_XH);
  float*          sq   = (float*)(ws + OFF_SQ);
  int*            labi = (int*)(ws + OFF_LAB);
  unsigned*       accu = (unsigned*)(ws + OFF_ACC);

  prep_kernel<<<NROWS / 4, 256, 0, stream>>>(X, lab, Xh, sq, labi, accu);
  pair_kernel<<<GRID, 256, 0, stream>>>(Xh, sq, labi, margin, (float*)accu, out);
}